// Round 9
// baseline (161.349 us; speedup 1.0000x reference)
//
#include <hip/hip_runtime.h>

typedef short bf16x8 __attribute__((ext_vector_type(8)));
typedef float f32x4 __attribute__((ext_vector_type(4)));
typedef unsigned short ushort8v __attribute__((ext_vector_type(8)));
typedef unsigned short ushort4v __attribute__((ext_vector_type(4)));
typedef unsigned int uint2v __attribute__((ext_vector_type(2)));

__device__ __forceinline__ unsigned short f2bf(float f) {
  unsigned u = __float_as_uint(f);
  u += 0x7FFF + ((u >> 16) & 1);   // round-to-nearest-even
  return (unsigned short)(u >> 16);
}

__device__ __forceinline__ unsigned cvt_pk_bf16(float lo, float hi) {
  unsigned r;
  asm("v_cvt_pk_bf16_f32 %0, %1, %2" : "=v"(r) : "v"(lo), "v"(hi));
  return r;
}

// ---------------------------------------------------------------------------
// Kernel 0: weights -> WbT [640][512] bf16 (Wq pre-scaled by log2e).
// ---------------------------------------------------------------------------
__global__ void wt_prep(const float* __restrict__ Wq, const float* __restrict__ Wk,
                        const float* __restrict__ Wv, unsigned short* __restrict__ WbT) {
  int idx = blockIdx.x * 256 + threadIdx.x;   // 640*512 = 327680 total
  int o = idx >> 9, c = idx & 511;
  float v;
  if (o < 64)       v = Wq[c * 64 + o] * 1.44269504f;
  else if (o < 128) v = Wk[c * 64 + (o - 64)];
  else              v = Wv[(size_t)c * 512 + (o - 128)];
  WbT[idx] = f2bf(v);
}

// ---------------------------------------------------------------------------
// Kernel 1: projection GEMM  [16384,512] x [512,640] -> q,k row-major bf16 and
// v transposed vT[b][512][4096] bf16. (validated rounds 3-7, unchanged)
// ---------------------------------------------------------------------------
__global__ __launch_bounds__(256, 2) void proj_gemm(
    const float* __restrict__ x, const unsigned short* __restrict__ WbT,
    unsigned short* __restrict__ q, unsigned short* __restrict__ k,
    unsigned short* __restrict__ vT) {
  __shared__ unsigned short As[128][72];   // 64 + 8 pad
  const int tid = threadIdx.x;
  const int wid = tid >> 6, lane = tid & 63;
  const int l15 = lane & 15, l4 = lane >> 4;
  const int mtile = blockIdx.x, ntile = blockIdx.y;
  const int rbase = mtile * 128;
  const int wr = (wid >> 1) * 64, wc = (wid & 1) * 64;

  f32x4 acc[4][4] = {};

  const int arow = tid >> 2;         // 0..63
  const int akof = (tid & 3) * 16;   // 0,16,32,48

  for (int kb = 0; kb < 512; kb += 64) {
    f32x4 t0[2][4];
#pragma unroll
    for (int pass = 0; pass < 2; ++pass) {
      const float* src = x + (size_t)(rbase + pass * 64 + arow) * 512 + kb + akof;
#pragma unroll
      for (int i = 0; i < 4; ++i) t0[pass][i] = *(const f32x4*)(src + i * 4);
    }
    __syncthreads();
#pragma unroll
    for (int pass = 0; pass < 2; ++pass) {
      unsigned short tmp[16];
#pragma unroll
      for (int i = 0; i < 4; ++i)
#pragma unroll
        for (int j = 0; j < 4; ++j) tmp[i * 4 + j] = f2bf(t0[pass][i][j]);
      unsigned short* dst = &As[pass * 64 + arow][akof];
      *(ushort8v*)(dst)     = *(ushort8v*)(tmp);
      *(ushort8v*)(dst + 8) = *(ushort8v*)(tmp + 8);
    }
    __syncthreads();

    bf16x8 af[4][2], bfr[4][2];
#pragma unroll
    for (int mr = 0; mr < 4; ++mr)
#pragma unroll
      for (int ks = 0; ks < 2; ++ks)
        af[mr][ks] = *(const bf16x8*)&As[wr + mr * 16 + l15][ks * 32 + l4 * 8];
#pragma unroll
    for (int nc = 0; nc < 4; ++nc)
#pragma unroll
      for (int ks = 0; ks < 2; ++ks) {
        int col = ntile * 128 + wc + nc * 16 + l15;
        bfr[nc][ks] = *(const bf16x8*)(WbT + (size_t)col * 512 + kb + ks * 32 + l4 * 8);
      }
#pragma unroll
    for (int ks = 0; ks < 2; ++ks)
#pragma unroll
      for (int mr = 0; mr < 4; ++mr)
#pragma unroll
        for (int nc = 0; nc < 4; ++nc)
          acc[mr][nc] = __builtin_amdgcn_mfma_f32_16x16x32_bf16(af[mr][ks], bfr[nc][ks],
                                                                acc[mr][nc], 0, 0, 0);
  }

  if (ntile == 0) {
    unsigned short* dst = (wid & 1) ? k : q;
#pragma unroll
    for (int mr = 0; mr < 4; ++mr)
#pragma unroll
      for (int nc = 0; nc < 4; ++nc)
#pragma unroll
        for (int r = 0; r < 4; ++r) {
          int grow = rbase + wr + mr * 16 + l4 * 4 + r;
          int col = nc * 16 + l15;
          dst[(size_t)grow * 64 + col] = f2bf(acc[mr][nc][r]);
        }
  } else {
#pragma unroll
    for (int mr = 0; mr < 4; ++mr)
#pragma unroll
      for (int nc = 0; nc < 4; ++nc) {
        int col = ntile * 128 + wc + nc * 16 + l15 - 128;   // 0..511
        int grow = rbase + wr + mr * 16 + l4 * 4;
        int b = grow >> 12, m = grow & 4095;
        ushort4v pk;
#pragma unroll
        for (int r = 0; r < 4; ++r) pk[r] = f2bf(acc[mr][nc][r]);
        *(ushort4v*)(vT + ((size_t)b * 512 + col) * 4096 + m) = pk;
      }
  }
}

// ---------------------------------------------------------------------------
// Kernel 2 (v6): fused sigmoid-attention.
// Grid (32 rt, 2 ct, 4 b) = 256 blocks x 512 threads (8 waves), 1 block/CU.
// Block: 128 q-rows x 256 v-cols; m-chunks of 64. K in registers (global,
// prefetched 1 chunk ahead). Vs TRIPLE-buffered, Ps double-buffered, both
// XOR-swizzled [row][64] (16B seg s^=(row&7)) -> all LDS ops at conflict
// floor. V global loads issued at iter top and CONSUMED (ds_write) BEFORE
// the barrier so the compiler's vmcnt(0) drain at the barrier waits nothing.
// One barrier per chunk. P packed via v_cvt_pk_bf16_f32.
// LDS = 3*32KB + 2*16KB = 128 KB.
// ---------------------------------------------------------------------------
__global__ __launch_bounds__(512, 1) void attn_fused(
    const float* __restrict__ x, const unsigned short* __restrict__ q,
    const unsigned short* __restrict__ k, const unsigned short* __restrict__ vT,
    const float* __restrict__ gamma, float* __restrict__ out) {
  __shared__ unsigned short Vs[3][256 * 64];   // 96 KB, swizzled
  __shared__ unsigned short Ps[2][128 * 64];   // 32 KB, swizzled
  const int tid = threadIdx.x, w = tid >> 6, lane = tid & 63;
  const int l15 = lane & 15, l4 = lane >> 4;
  const int rhalf = w >> 2;      // 0..1: q-row half (S rows, PV row-group)
  const int mt = w & 3;          // 0..3: m-tile (S) / PV col-group
  const int rt = blockIdx.x, ct = blockIdx.y, b = blockIdx.z;
  const int rbase = rt * 128, cbase = ct * 256;
  const unsigned short* qb = q + (size_t)b * 4096 * 64;
  const unsigned short* kp = k + (size_t)b * 4096 * 64;
  const unsigned short* vb = vT + (size_t)b * 512 * 4096;
  const float gv = gamma[0];

  // V staging: 512 threads x 64 B; thread -> row vst_c, segs (vst_x*4 + i)
  const int vst_c = tid >> 1, vst_x = tid & 1;

  // q fragments, register-resident for all 64 chunks
  bf16x8 qf[4][2];
#pragma unroll
  for (int rf = 0; rf < 4; ++rf)
#pragma unroll
    for (int ks = 0; ks < 2; ++ks)
      qf[rf][ks] = *(const bf16x8*)(qb +
          (size_t)(rbase + rhalf * 64 + rf * 16 + l15) * 64 + ks * 32 + l4 * 8);

  // ---- prologue: K(0) frags to regs; stage V(0) into Vs[0] (swizzled) ----
  bf16x8 kfc[2];
#pragma unroll
  for (int ks = 0; ks < 2; ++ks)
    kfc[ks] = *(const bf16x8*)(kp + (size_t)(mt * 16 + l15) * 64 + ks * 32 + l4 * 8);
  {
    bf16x8 vv[4];
#pragma unroll
    for (int i = 0; i < 4; ++i)
      vv[i] = *(const bf16x8*)(vb + (size_t)(cbase + vst_c) * 4096 + vst_x * 32 + i * 8);
#pragma unroll
    for (int i = 0; i < 4; ++i)
      *(bf16x8*)&Vs[0][vst_c * 64 + ((vst_x * 4 + i) ^ (vst_c & 7)) * 8] = vv[i];
  }

  f32x4 oacc[4][4] = {};
  int cur = 0;

  for (int it = 0; it < 64; ++it) {
    const int mb_n = (it + 1) * 64;
    const bool pf = (it < 63);
    const int p = it & 1;
    int wbuf = cur + 1; if (wbuf == 3) wbuf = 0;
    bf16x8 kfn[2], vv[4];
    if (pf) {   // issue next chunk's global loads (consumed before the barrier)
#pragma unroll
      for (int ks = 0; ks < 2; ++ks)
        kfn[ks] = *(const bf16x8*)(kp + (size_t)(mb_n + mt * 16 + l15) * 64 + ks * 32 + l4 * 8);
#pragma unroll
      for (int i = 0; i < 4; ++i)
        vv[i] = *(const bf16x8*)(vb + (size_t)(cbase + vst_c) * 4096 + mb_n + vst_x * 32 + i * 8);
    }

    // ---- S^T = K.Q^T : wave (rhalf,mt): m-tile mt (16 m) x 64 q-rows ----
    f32x4 sacc[4] = {};
#pragma unroll
    for (int ks = 0; ks < 2; ++ks)
#pragma unroll
      for (int rf = 0; rf < 4; ++rf)
        sacc[rf] = __builtin_amdgcn_mfma_f32_16x16x32_bf16(kfc[ks], qf[rf][ks], sacc[rf], 0, 0, 0);

    // ---- sigmoid + cvt_pk pack -> swizzled b64 P write ----
#pragma unroll
    for (int rf = 0; rf < 4; ++rf) {
      float pv[4];
#pragma unroll
      for (int r = 0; r < 4; ++r)
        pv[r] = __builtin_amdgcn_rcpf(1.0f + __builtin_amdgcn_exp2f(-sacc[rf][r]));
      uint2v pk;
      pk[0] = cvt_pk_bf16(pv[0], pv[1]);
      pk[1] = cvt_pk_bf16(pv[2], pv[3]);
      int row = rhalf * 64 + rf * 16 + l15;
      int seg = 2 * mt + (l4 >> 1);
      *(uint2v*)&Ps[p][row * 64 + ((seg ^ (row & 7)) << 3) + (l4 & 1) * 4] = pk;
    }

    // ---- consume prefetched V/K BEFORE the barrier (nothing spans it) ----
    if (pf) {
#pragma unroll
      for (int i = 0; i < 4; ++i)
        *(bf16x8*)&Vs[wbuf][vst_c * 64 + ((vst_x * 4 + i) ^ (vst_c & 7)) * 8] = vv[i];
      kfc[0] = kfn[0]; kfc[1] = kfn[1];
    }
    __syncthreads();   // the ONLY barrier per chunk

    // ---- O += P.v : wave rows rhalf*64(+64), cols mt*64(+64) ----
    __builtin_amdgcn_s_setprio(1);
#pragma unroll
    for (int kk = 0; kk < 2; ++kk) {
      bf16x8 af[4], bfr[4];
#pragma unroll
      for (int mr = 0; mr < 4; ++mr) {
        int row = rhalf * 64 + mr * 16 + l15;
        af[mr] = *(const bf16x8*)&Ps[p][row * 64 + (((kk * 4 + l4) ^ (row & 7)) << 3)];
      }
#pragma unroll
      for (int nc = 0; nc < 4; ++nc) {
        int rowv = mt * 64 + nc * 16 + l15;
        bfr[nc] = *(const bf16x8*)&Vs[cur][rowv * 64 + (((kk * 4 + l4) ^ (rowv & 7)) << 3)];
      }
#pragma unroll
      for (int mr = 0; mr < 4; ++mr)
#pragma unroll
        for (int nc = 0; nc < 4; ++nc)
          oacc[mr][nc] = __builtin_amdgcn_mfma_f32_16x16x32_bf16(af[mr], bfr[nc],
                                                                 oacc[mr][nc], 0, 0, 0);
    }
    __builtin_amdgcn_s_setprio(0);
    cur = wbuf;
  }

  // ---- epilogue: out = gamma * O + x ----
#pragma unroll
  for (int mr = 0; mr < 4; ++mr)
#pragma unroll
    for (int nc = 0; nc < 4; ++nc)
#pragma unroll
      for (int r = 0; r < 4; ++r) {
        int grow = rbase + rhalf * 64 + mr * 16 + l4 * 4 + r;
        int col = cbase + mt * 64 + nc * 16 + l15;
        size_t idx = ((size_t)b * 4096 + grow) * 512 + col;
        out[idx] = gv * oacc[mr][nc][r] + x[idx];
      }
}

extern "C" void kernel_launch(void* const* d_in, const int* in_sizes, int n_in,
                              void* d_out, int out_size, void* d_ws, size_t ws_size,
                              hipStream_t stream) {
  const float* x     = (const float*)d_in[0];
  const float* Wq    = (const float*)d_in[1];
  const float* Wk    = (const float*)d_in[2];
  const float* Wv    = (const float*)d_in[3];
  const float* gamma = (const float*)d_in[4];
  float* out = (float*)d_out;

  char* ws = (char*)d_ws;
  unsigned short* qbuf = (unsigned short*)(ws);                       // 2 MB
  unsigned short* kbuf = (unsigned short*)(ws + (2ull << 20));        // 2 MB
  unsigned short* vT   = (unsigned short*)(ws + (4ull << 20));        // 16 MB
  unsigned short* WbT  = (unsigned short*)(ws + (20ull << 20));       // 640 KB

  hipLaunchKernelGGL(wt_prep, dim3(1280), dim3(256), 0, stream, Wq, Wk, Wv, WbT);
  hipLaunchKernelGGL(proj_gemm, dim3(128, 5), dim3(256), 0, stream, x, WbT, qbuf, kbuf, vT);
  hipLaunchKernelGGL(attn_fused, dim3(32, 2, 4), dim3(512), 0, stream,
                     x, qbuf, kbuf, vT, gamma, out);
}